// Round 1
// baseline (1010.824 us; speedup 1.0000x reference)
//
#include <hip/hip_runtime.h>
#include <math.h>

#define DD 128
#define CC 40

// ---------------------------------------------------------------------------
// Detect edge_index storage: int32 (JAX default, x64 off) vs int64.
// int64 little-endian with values in [0,1e5): every odd 32-bit word == 0.
// flag = 1 -> int32, flag = 0 -> int64.
__global__ void detect_kernel(const unsigned* __restrict__ e, int* __restrict__ flag) {
    int t = threadIdx.x;
    unsigned nz = 0;
    for (int j = 0; j < 16; ++j) nz |= e[2 * (t * 16 + j) + 1];
    unsigned long long b = __ballot(nz != 0);
    if (t == 0) *flag = (b != 0) ? 1 : 0;
}

__device__ __forceinline__ int edge_at(const void* eptr, int is32, long long idx) {
    if (is32) return ((const int*)eptr)[idx];
    return (int)((const long long*)eptr)[idx];
}

// In-degree histogram over dst (row = edge_index[0]).
__global__ void hist_kernel(const void* __restrict__ eptr, int* __restrict__ cnt,
                            const int* __restrict__ flag, int E) {
    int e = blockIdx.x * blockDim.x + threadIdx.x;
    if (e >= E) return;
    int is32 = *flag;
    int r = edge_at(eptr, is32, e);
    atomicAdd(&cnt[r], 1);
}

// Single-block chunked exclusive scan: row_ptr from cnt; also dinv = rsqrt(deg+1)
// and resets cnt to 0 (reused as scatter cursor).
__global__ __launch_bounds__(1024) void scan_kernel(int* __restrict__ cnt,
                                                    int* __restrict__ row_ptr,
                                                    float* __restrict__ dinv, int N) {
    __shared__ int swave[16];
    __shared__ int s_run;
    int tid = threadIdx.x;
    int lane = tid & 63, wid = tid >> 6;
    if (tid == 0) s_run = 0;
    __syncthreads();
    for (int base = 0; base < N; base += 1024) {
        int i = base + tid;
        int v = (i < N) ? cnt[i] : 0;
        int incl = v;
#pragma unroll
        for (int off = 1; off < 64; off <<= 1) {
            int t = __shfl_up(incl, off);
            if (lane >= off) incl += t;
        }
        if (lane == 63) swave[wid] = incl;
        __syncthreads();
        if (tid < 16) {
            int t = swave[tid];
#pragma unroll
            for (int off = 1; off < 16; off <<= 1) {
                int u = __shfl_up(t, off);
                if (tid >= off) t += u;
            }
            swave[tid] = t;
        }
        __syncthreads();
        int waveoff = (wid == 0) ? 0 : swave[wid - 1];
        int run = s_run;
        if (i < N) {
            row_ptr[i] = run + waveoff + incl - v;   // exclusive prefix
            dinv[i] = rsqrtf((float)v + 1.0f);       // deg = in_deg + 1 (self loop)
            cnt[i] = 0;                              // reset for scatter cursor
        }
        __syncthreads();
        if (tid == 0) s_run = run + swave[15];
        __syncthreads();
    }
    if (tid == 0) row_ptr[N] = s_run;
}

// CSR scatter: csr[row_ptr[dst] + cursor++] = src
__global__ void scatter_kernel(const void* __restrict__ eptr, const int* __restrict__ row_ptr,
                               int* __restrict__ cursor, int* __restrict__ csr,
                               const int* __restrict__ flag, int E) {
    int e = blockIdx.x * blockDim.x + threadIdx.x;
    if (e >= E) return;
    int is32 = *flag;
    int r = edge_at(eptr, is32, e);
    int c = edge_at(eptr, is32, (long long)E + e);
    int pos = row_ptr[r] + atomicAdd(&cursor[r], 1);
    csr[pos] = c;
}

// ---------------------------------------------------------------------------
// Y[N,128] = X[N,128] @ W[128,128], fp32, LDS-tiled.
// Block: 256 threads -> 32-row x 128-col output tile; requires N % 32 == 0.
__global__ __launch_bounds__(256) void matmul_kernel(const float* __restrict__ X,
                                                     const float* __restrict__ W,
                                                     float* __restrict__ Y, int N) {
    __shared__ float Ws[32][DD];   // 16 KB
    __shared__ float Xs[32][32];   // 4 KB
    int block_row = blockIdx.x * 32;
    int t = threadIdx.x;
    int tc = t & 31;   // col group: cols [tc*4, tc*4+4)
    int tr = t >> 5;   // row group: rows [tr*4, tr*4+4)
    float4 acc[4];
#pragma unroll
    for (int r = 0; r < 4; ++r) acc[r] = make_float4(0.f, 0.f, 0.f, 0.f);

    for (int k0 = 0; k0 < DD; k0 += 32) {
        // stage W[k0..k0+32][:]: 4096 floats, 4 float4 per thread, coalesced
#pragma unroll
        for (int j = 0; j < 4; ++j) {
            int flat = (j * 256 + t) * 4;
            int kk = flat >> 7, cc = flat & 127;
            *(float4*)&Ws[kk][cc] = *(const float4*)&W[(size_t)(k0 + kk) * DD + cc];
        }
        // stage X[block_row..+32][k0..k0+32]: 1024 floats, 1 float4 per thread
        {
            int flat = t * 4;
            int rr = flat >> 5, cc = flat & 31;
            *(float4*)&Xs[rr][cc] = *(const float4*)&X[(size_t)(block_row + rr) * DD + k0 + cc];
        }
        __syncthreads();
#pragma unroll
        for (int kk = 0; kk < 32; ++kk) {
            float4 w = *(float4*)&Ws[kk][tc * 4];
#pragma unroll
            for (int r = 0; r < 4; ++r) {
                float a = Xs[tr * 4 + r][kk];
                acc[r].x = fmaf(a, w.x, acc[r].x);
                acc[r].y = fmaf(a, w.y, acc[r].y);
                acc[r].z = fmaf(a, w.z, acc[r].z);
                acc[r].w = fmaf(a, w.w, acc[r].w);
            }
        }
        __syncthreads();
    }
#pragma unroll
    for (int r = 0; r < 4; ++r) {
        int row = block_row + tr * 4 + r;
        *(float4*)&Y[(size_t)row * DD + tc * 4] = acc[r];
    }
}

// ---------------------------------------------------------------------------
// Fused: CSR gather-agg + self loop + bias + BN(eval) + ReLU + JK running max.
// One 32-lane group per node; each lane owns 4 channels (float4).
__global__ __launch_bounds__(256) void agg_kernel(
    const float* __restrict__ h1, const int* __restrict__ row_ptr,
    const int* __restrict__ csr, const float* __restrict__ dinv,
    const float* __restrict__ bias, const float* __restrict__ gamma,
    const float* __restrict__ beta, const float* __restrict__ mean,
    const float* __restrict__ var, float* __restrict__ hout,
    float* __restrict__ jk, int first, int N) {
    int gid = (blockIdx.x * blockDim.x + threadIdx.x) >> 5;
    if (gid >= N) return;
    int lane = threadIdx.x & 31;
    int c = lane * 4;

    int s = row_ptr[gid], e = row_ptr[gid + 1];
    float4 acc = make_float4(0.f, 0.f, 0.f, 0.f);
    for (int p = s; p < e; ++p) {
        int src = csr[p];
        float w = dinv[src];
        float4 v = *(const float4*)&h1[(size_t)src * DD + c];
        acc.x = fmaf(w, v.x, acc.x);
        acc.y = fmaf(w, v.y, acc.y);
        acc.z = fmaf(w, v.z, acc.z);
        acc.w = fmaf(w, v.w, acc.w);
    }
    float di = dinv[gid];
    float sn = di * di;                       // self_norm = 1/deg
    float4 self = *(const float4*)&h1[(size_t)gid * DD + c];
    float4 b4 = *(const float4*)&bias[c];
    float4 g4 = *(const float4*)&gamma[c];
    float4 be4 = *(const float4*)&beta[c];
    float4 m4 = *(const float4*)&mean[c];
    float4 v4 = *(const float4*)&var[c];

    float hx = fmaf(di, acc.x, fmaf(sn, self.x, b4.x));
    float hy = fmaf(di, acc.y, fmaf(sn, self.y, b4.y));
    float hz = fmaf(di, acc.z, fmaf(sn, self.z, b4.z));
    float hw = fmaf(di, acc.w, fmaf(sn, self.w, b4.w));

    float ox = fmaxf(g4.x * (hx - m4.x) * rsqrtf(v4.x + 1e-5f) + be4.x, 0.f);
    float oy = fmaxf(g4.y * (hy - m4.y) * rsqrtf(v4.y + 1e-5f) + be4.y, 0.f);
    float oz = fmaxf(g4.z * (hz - m4.z) * rsqrtf(v4.z + 1e-5f) + be4.z, 0.f);
    float ow = fmaxf(g4.w * (hw - m4.w) * rsqrtf(v4.w + 1e-5f) + be4.w, 0.f);
    float4 o = make_float4(ox, oy, oz, ow);

    *(float4*)&hout[(size_t)gid * DD + c] = o;
    size_t ji = (size_t)gid * DD + c;
    if (first) {
        *(float4*)&jk[ji] = o;
    } else {
        float4 old = *(const float4*)&jk[ji];
        *(float4*)&jk[ji] = make_float4(fmaxf(old.x, o.x), fmaxf(old.y, o.y),
                                        fmaxf(old.z, o.z), fmaxf(old.w, o.w));
    }
}

// ---------------------------------------------------------------------------
// logits = jk @ lin_w + lin_b; log_softmax per row. One wave per node.
__global__ __launch_bounds__(256) void final_kernel(const float* __restrict__ jk,
                                                    const float* __restrict__ lw,
                                                    const float* __restrict__ lb,
                                                    float* __restrict__ out, int N) {
    int wid = (blockIdx.x * blockDim.x + threadIdx.x) >> 6;
    if (wid >= N) return;
    int lane = threadIdx.x & 63;
    const float* row = &jk[(size_t)wid * DD];
    float acc = (lane < CC) ? lb[lane] : 0.0f;
#pragma unroll 4
    for (int k = 0; k < DD; ++k) {
        float a = row[k];
        float w = (lane < CC) ? lw[k * CC + lane] : 0.0f;
        acc = fmaf(a, w, acc);
    }
    float lg = (lane < CC) ? acc : -1e30f;
    float m = lg;
#pragma unroll
    for (int off = 32; off > 0; off >>= 1) m = fmaxf(m, __shfl_xor(m, off));
    float ex = (lane < CC) ? expf(acc - m) : 0.0f;
    float ssum = ex;
#pragma unroll
    for (int off = 32; off > 0; off >>= 1) ssum += __shfl_xor(ssum, off);
    if (lane < CC) out[(size_t)wid * CC + lane] = acc - m - logf(ssum);
}

// ---------------------------------------------------------------------------
extern "C" void kernel_launch(void* const* d_in, const int* in_sizes, int n_in,
                              void* d_out, int out_size, void* d_ws, size_t ws_size,
                              hipStream_t stream) {
    const float* x      = (const float*)d_in[0];
    const void*  eidx   = d_in[1];
    const float* conv_w = (const float*)d_in[2];
    const float* conv_b = (const float*)d_in[3];
    const float* gamma  = (const float*)d_in[4];
    const float* beta   = (const float*)d_in[5];
    const float* mean   = (const float*)d_in[6];
    const float* var    = (const float*)d_in[7];
    const float* lin_w  = (const float*)d_in[8];
    const float* lin_b  = (const float*)d_in[9];
    float* out = (float*)d_out;

    const int N = in_sizes[0] / DD;      // 100000
    const int E = in_sizes[1] / 2;       // 800000
    const int L = in_sizes[3] / DD;      // 5

    // workspace carve-up (~161 MB total)
    char* p = (char*)d_ws;
    auto alloc = [&](size_t bytes) -> char* {
        char* r = p;
        p += (bytes + 255) & ~(size_t)255;
        return r;
    };
    float* h_cur   = (float*)alloc((size_t)N * DD * 4);
    float* h1      = (float*)alloc((size_t)N * DD * 4);
    float* jk      = (float*)alloc((size_t)N * DD * 4);
    float* dinv    = (float*)alloc((size_t)N * 4);
    int*   row_ptr = (int*)alloc((size_t)(N + 1) * 4);
    int*   cnt     = (int*)alloc((size_t)N * 4);
    int*   csr     = (int*)alloc((size_t)E * 4);
    int*   flag    = (int*)alloc(4);

    detect_kernel<<<1, 64, 0, stream>>>((const unsigned*)eidx, flag);
    hipMemsetAsync(cnt, 0, (size_t)N * 4, stream);
    hist_kernel<<<(E + 255) / 256, 256, 0, stream>>>(eidx, cnt, flag, E);
    scan_kernel<<<1, 1024, 0, stream>>>(cnt, row_ptr, dinv, N);
    scatter_kernel<<<(E + 255) / 256, 256, 0, stream>>>(eidx, row_ptr, cnt, csr, flag, E);

    const float* X = x;
    for (int l = 0; l < L; ++l) {
        matmul_kernel<<<N / 32, 256, 0, stream>>>(X, conv_w + (size_t)l * DD * DD, h1, N);
        agg_kernel<<<(N * 32 + 255) / 256, 256, 0, stream>>>(
            h1, row_ptr, csr, dinv,
            conv_b + (size_t)l * DD, gamma + (size_t)l * DD, beta + (size_t)l * DD,
            mean + (size_t)l * DD, var + (size_t)l * DD,
            h_cur, jk, (l == 0) ? 1 : 0, N);
        X = h_cur;
    }
    final_kernel<<<((size_t)N * 64 + 255) / 256, 256, 0, stream>>>(jk, lin_w, lin_b, out, N);
}

// Round 2
// 767.463 us; speedup vs baseline: 1.3171x; 1.3171x over previous
//
#include <hip/hip_runtime.h>
#include <math.h>

#define DD 128
#define CC 40

// ---------------------------------------------------------------------------
// Detect edge_index storage: int32 (JAX default, x64 off) vs int64.
// int64 little-endian with values in [0,1e5): every odd 32-bit word == 0.
// flag = 1 -> int32, flag = 0 -> int64.
__global__ void detect_kernel(const unsigned* __restrict__ e, int* __restrict__ flag) {
    int t = threadIdx.x;
    unsigned nz = 0;
    for (int j = 0; j < 16; ++j) nz |= e[2 * (t * 16 + j) + 1];
    unsigned long long b = __ballot(nz != 0);
    if (t == 0) *flag = (b != 0) ? 1 : 0;
}

__device__ __forceinline__ int edge_at(const void* eptr, int is32, long long idx) {
    if (is32) return ((const int*)eptr)[idx];
    return (int)((const long long*)eptr)[idx];
}

// In-degree histogram over dst (row = edge_index[0]).
__global__ void hist_kernel(const void* __restrict__ eptr, int* __restrict__ cnt,
                            const int* __restrict__ flag, int E) {
    int e = blockIdx.x * blockDim.x + threadIdx.x;
    if (e >= E) return;
    int is32 = *flag;
    int r = edge_at(eptr, is32, e);
    atomicAdd(&cnt[r], 1);
}

// ---------------------------------------------------------------------------
// Hierarchical exclusive scan over cnt[N] (chunk = 1024 per block).
// scanA: per-block scan -> local exclusive in row_ptr, block total in blksum.
//        Also writes dinv = rsqrt(deg+1) and resets cnt (reused as cursor).
__global__ __launch_bounds__(1024) void scanA_kernel(int* __restrict__ cnt,
                                                     int* __restrict__ row_ptr,
                                                     float* __restrict__ dinv,
                                                     int* __restrict__ blksum, int N) {
    __shared__ int swave[16];
    int tid = threadIdx.x;
    int lane = tid & 63, wid = tid >> 6;
    int i = blockIdx.x * 1024 + tid;
    int v = (i < N) ? cnt[i] : 0;
    int incl = v;
#pragma unroll
    for (int off = 1; off < 64; off <<= 1) {
        int t = __shfl_up(incl, off);
        if (lane >= off) incl += t;
    }
    if (lane == 63) swave[wid] = incl;
    __syncthreads();
    if (tid < 16) {
        int t = swave[tid];
#pragma unroll
        for (int off = 1; off < 16; off <<= 1) {
            int u = __shfl_up(t, off);
            if (tid >= off) t += u;
        }
        swave[tid] = t;
    }
    __syncthreads();
    int waveoff = (wid == 0) ? 0 : swave[wid - 1];
    if (i < N) {
        row_ptr[i] = waveoff + incl - v;        // block-local exclusive
        dinv[i] = rsqrtf((float)v + 1.0f);      // deg = in_deg + 1 (self loop)
        cnt[i] = 0;                             // reset for scatter cursor
    }
    if (tid == 0) blksum[blockIdx.x] = swave[15];
}

// scanB: exclusive scan of block totals (nb <= 128) in one block.
__global__ __launch_bounds__(128) void scanB_kernel(int* __restrict__ blksum, int nb) {
    __shared__ int s[128];
    int t = threadIdx.x;
    int orig = (t < nb) ? blksum[t] : 0;
    s[t] = orig;
    __syncthreads();
    for (int off = 1; off < 128; off <<= 1) {
        int v = (t >= off) ? s[t - off] : 0;
        __syncthreads();
        s[t] += v;
        __syncthreads();
    }
    if (t < nb) blksum[t] = s[t] - orig;        // exclusive
}

// scanC: add block offsets; set row_ptr[N] = E.
__global__ void scanC_kernel(int* __restrict__ row_ptr, const int* __restrict__ blksum,
                             int N, int E) {
    int i = blockIdx.x * blockDim.x + threadIdx.x;
    if (i < N) row_ptr[i] += blksum[i >> 10];
    if (i == 0) row_ptr[N] = E;
}

// CSR scatter: csr[row_ptr[dst] + cursor++] = src
__global__ void scatter_kernel(const void* __restrict__ eptr, const int* __restrict__ row_ptr,
                               int* __restrict__ cursor, int* __restrict__ csr,
                               const int* __restrict__ flag, int E) {
    int e = blockIdx.x * blockDim.x + threadIdx.x;
    if (e >= E) return;
    int is32 = *flag;
    int r = edge_at(eptr, is32, e);
    int c = edge_at(eptr, is32, (long long)E + e);
    int pos = row_ptr[r] + atomicAdd(&cursor[r], 1);
    csr[pos] = c;
}

// ---------------------------------------------------------------------------
// Y[N,128] = X[N,128] @ W[128,128], fp32, LDS-tiled.
// Block: 256 threads -> 32-row x 128-col output tile; requires N % 32 == 0.
__global__ __launch_bounds__(256) void matmul_kernel(const float* __restrict__ X,
                                                     const float* __restrict__ W,
                                                     float* __restrict__ Y, int N) {
    __shared__ float Ws[32][DD];   // 16 KB
    __shared__ float Xs[32][32];   // 4 KB
    int block_row = blockIdx.x * 32;
    int t = threadIdx.x;
    int tc = t & 31;   // col group: cols [tc*4, tc*4+4)
    int tr = t >> 5;   // row group: rows [tr*4, tr*4+4)
    float4 acc[4];
#pragma unroll
    for (int r = 0; r < 4; ++r) acc[r] = make_float4(0.f, 0.f, 0.f, 0.f);

    for (int k0 = 0; k0 < DD; k0 += 32) {
#pragma unroll
        for (int j = 0; j < 4; ++j) {
            int flat = (j * 256 + t) * 4;
            int kk = flat >> 7, cc = flat & 127;
            *(float4*)&Ws[kk][cc] = *(const float4*)&W[(size_t)(k0 + kk) * DD + cc];
        }
        {
            int flat = t * 4;
            int rr = flat >> 5, cc = flat & 31;
            *(float4*)&Xs[rr][cc] = *(const float4*)&X[(size_t)(block_row + rr) * DD + k0 + cc];
        }
        __syncthreads();
#pragma unroll
        for (int kk = 0; kk < 32; ++kk) {
            float4 w = *(float4*)&Ws[kk][tc * 4];
#pragma unroll
            for (int r = 0; r < 4; ++r) {
                float a = Xs[tr * 4 + r][kk];
                acc[r].x = fmaf(a, w.x, acc[r].x);
                acc[r].y = fmaf(a, w.y, acc[r].y);
                acc[r].z = fmaf(a, w.z, acc[r].z);
                acc[r].w = fmaf(a, w.w, acc[r].w);
            }
        }
        __syncthreads();
    }
#pragma unroll
    for (int r = 0; r < 4; ++r) {
        int row = block_row + tr * 4 + r;
        *(float4*)&Y[(size_t)row * DD + tc * 4] = acc[r];
    }
}

// ---------------------------------------------------------------------------
// Fused: CSR gather-agg + self loop + bias + BN(eval) + ReLU + JK running max.
// One 32-lane group per node; each lane owns 4 channels (float4).
__global__ __launch_bounds__(256) void agg_kernel(
    const float* __restrict__ h1, const int* __restrict__ row_ptr,
    const int* __restrict__ csr, const float* __restrict__ dinv,
    const float* __restrict__ bias, const float* __restrict__ gamma,
    const float* __restrict__ beta, const float* __restrict__ mean,
    const float* __restrict__ var, float* __restrict__ hout,
    float* __restrict__ jk, int first, int N) {
    int gid = (blockIdx.x * blockDim.x + threadIdx.x) >> 5;
    if (gid >= N) return;
    int lane = threadIdx.x & 31;
    int c = lane * 4;

    int s = row_ptr[gid], e = row_ptr[gid + 1];
    float4 acc = make_float4(0.f, 0.f, 0.f, 0.f);
    for (int p = s; p < e; ++p) {
        int src = csr[p];
        float w = dinv[src];
        float4 v = *(const float4*)&h1[(size_t)src * DD + c];
        acc.x = fmaf(w, v.x, acc.x);
        acc.y = fmaf(w, v.y, acc.y);
        acc.z = fmaf(w, v.z, acc.z);
        acc.w = fmaf(w, v.w, acc.w);
    }
    float di = dinv[gid];
    float sn = di * di;                       // self_norm = 1/deg
    float4 self = *(const float4*)&h1[(size_t)gid * DD + c];
    float4 b4 = *(const float4*)&bias[c];
    float4 g4 = *(const float4*)&gamma[c];
    float4 be4 = *(const float4*)&beta[c];
    float4 m4 = *(const float4*)&mean[c];
    float4 v4 = *(const float4*)&var[c];

    float hx = fmaf(di, acc.x, fmaf(sn, self.x, b4.x));
    float hy = fmaf(di, acc.y, fmaf(sn, self.y, b4.y));
    float hz = fmaf(di, acc.z, fmaf(sn, self.z, b4.z));
    float hw = fmaf(di, acc.w, fmaf(sn, self.w, b4.w));

    float ox = fmaxf(g4.x * (hx - m4.x) * rsqrtf(v4.x + 1e-5f) + be4.x, 0.f);
    float oy = fmaxf(g4.y * (hy - m4.y) * rsqrtf(v4.y + 1e-5f) + be4.y, 0.f);
    float oz = fmaxf(g4.z * (hz - m4.z) * rsqrtf(v4.z + 1e-5f) + be4.z, 0.f);
    float ow = fmaxf(g4.w * (hw - m4.w) * rsqrtf(v4.w + 1e-5f) + be4.w, 0.f);
    float4 o = make_float4(ox, oy, oz, ow);

    *(float4*)&hout[(size_t)gid * DD + c] = o;
    size_t ji = (size_t)gid * DD + c;
    if (first) {
        *(float4*)&jk[ji] = o;
    } else {
        float4 old = *(const float4*)&jk[ji];
        *(float4*)&jk[ji] = make_float4(fmaxf(old.x, o.x), fmaxf(old.y, o.y),
                                        fmaxf(old.z, o.z), fmaxf(old.w, o.w));
    }
}

// ---------------------------------------------------------------------------
// out = log_softmax(jk @ lin_w + lin_b). Tiled: 256 nodes/block.
// LDS: lin_w (128x40) + transposed jk k-slab (32 x 256, padded).
// Thread t: og = t&3 -> classes [og*10, og*10+10); ng = t>>2 -> nodes
// [ng*4, ng*4+4). 40 fp32 accumulators. W reads are wave-broadcast float2.
__global__ __launch_bounds__(256) void final_kernel(const float* __restrict__ jk,
                                                    const float* __restrict__ lw,
                                                    const float* __restrict__ lb,
                                                    float* __restrict__ out, int N) {
    __shared__ float Ws[DD][CC];     // 20.0 KB
    __shared__ float Xs[32][260];    // 32.5 KB (pad 260: 16B-aligned rows, ~2-way banks)
    __shared__ float lbS[CC];
    int t = threadIdx.x;
    for (int i = t; i < DD * CC; i += 256) Ws[i / CC][i % CC] = lw[i];
    if (t < CC) lbS[t] = lb[t];
    int base = blockIdx.x * 256;
    int og = t & 3, ng = t >> 2;
    __syncthreads();

    float acc[4][10];
#pragma unroll
    for (int r = 0; r < 4; ++r)
#pragma unroll
        for (int c = 0; c < 10; ++c) acc[r][c] = lbS[og * 10 + c];

    for (int k0 = 0; k0 < DD; k0 += 32) {
        __syncthreads();
#pragma unroll
        for (int chunk = 0; chunk < 8; ++chunk) {
            int f = chunk * 256 + t;       // float4 id within slab
            int nl = f >> 3;               // node local 0..255
            int kk = (f & 7) * 4;
            int node = base + nl;
            float4 v = make_float4(0.f, 0.f, 0.f, 0.f);
            if (node < N) v = *(const float4*)&jk[(size_t)node * DD + k0 + kk];
            Xs[kk + 0][nl] = v.x;
            Xs[kk + 1][nl] = v.y;
            Xs[kk + 2][nl] = v.z;
            Xs[kk + 3][nl] = v.w;
        }
        __syncthreads();
#pragma unroll 4
        for (int kk = 0; kk < 32; ++kk) {
            float4 xv = *(const float4*)&Xs[kk][ng * 4];
#pragma unroll
            for (int cc2 = 0; cc2 < 5; ++cc2) {
                float2 w2 = *(const float2*)&Ws[k0 + kk][og * 10 + cc2 * 2];
                int c0 = cc2 * 2, c1 = cc2 * 2 + 1;
                acc[0][c0] = fmaf(xv.x, w2.x, acc[0][c0]);
                acc[1][c0] = fmaf(xv.y, w2.x, acc[1][c0]);
                acc[2][c0] = fmaf(xv.z, w2.x, acc[2][c0]);
                acc[3][c0] = fmaf(xv.w, w2.x, acc[3][c0]);
                acc[0][c1] = fmaf(xv.x, w2.y, acc[0][c1]);
                acc[1][c1] = fmaf(xv.y, w2.y, acc[1][c1]);
                acc[2][c1] = fmaf(xv.z, w2.y, acc[2][c1]);
                acc[3][c1] = fmaf(xv.w, w2.y, acc[3][c1]);
            }
        }
    }

    // per-node log-softmax: reduce across the 4 og lanes (t^1, t^2 share ng)
#pragma unroll
    for (int r = 0; r < 4; ++r) {
        int node = base + ng * 4 + r;
        float m = acc[r][0];
#pragma unroll
        for (int c = 1; c < 10; ++c) m = fmaxf(m, acc[r][c]);
        m = fmaxf(m, __shfl_xor(m, 1));
        m = fmaxf(m, __shfl_xor(m, 2));
        float s = 0.f;
#pragma unroll
        for (int c = 0; c < 10; ++c) s += expf(acc[r][c] - m);
        s += __shfl_xor(s, 1);
        s += __shfl_xor(s, 2);
        float lg = logf(s);
        if (node < N) {
#pragma unroll
            for (int c = 0; c < 10; ++c)
                out[(size_t)node * CC + og * 10 + c] = acc[r][c] - m - lg;
        }
    }
}

// ---------------------------------------------------------------------------
extern "C" void kernel_launch(void* const* d_in, const int* in_sizes, int n_in,
                              void* d_out, int out_size, void* d_ws, size_t ws_size,
                              hipStream_t stream) {
    const float* x      = (const float*)d_in[0];
    const void*  eidx   = d_in[1];
    const float* conv_w = (const float*)d_in[2];
    const float* conv_b = (const float*)d_in[3];
    const float* gamma  = (const float*)d_in[4];
    const float* beta   = (const float*)d_in[5];
    const float* mean   = (const float*)d_in[6];
    const float* var    = (const float*)d_in[7];
    const float* lin_w  = (const float*)d_in[8];
    const float* lin_b  = (const float*)d_in[9];
    float* out = (float*)d_out;

    const int N = in_sizes[0] / DD;      // 100000
    const int E = in_sizes[1] / 2;       // 800000
    const int L = in_sizes[3] / DD;      // 5
    const int NB = (N + 1023) / 1024;    // scan blocks (<=128)

    char* p = (char*)d_ws;
    auto alloc = [&](size_t bytes) -> char* {
        char* r = p;
        p += (bytes + 255) & ~(size_t)255;
        return r;
    };
    float* h_cur   = (float*)alloc((size_t)N * DD * 4);
    float* h1      = (float*)alloc((size_t)N * DD * 4);
    float* jk      = (float*)alloc((size_t)N * DD * 4);
    float* dinv    = (float*)alloc((size_t)N * 4);
    int*   row_ptr = (int*)alloc((size_t)(N + 1) * 4);
    int*   cnt     = (int*)alloc((size_t)N * 4);
    int*   csr     = (int*)alloc((size_t)E * 4);
    int*   blksum  = (int*)alloc(128 * 4);
    int*   flag    = (int*)alloc(4);

    detect_kernel<<<1, 64, 0, stream>>>((const unsigned*)eidx, flag);
    hipMemsetAsync(cnt, 0, (size_t)N * 4, stream);
    hist_kernel<<<(E + 255) / 256, 256, 0, stream>>>(eidx, cnt, flag, E);
    scanA_kernel<<<NB, 1024, 0, stream>>>(cnt, row_ptr, dinv, blksum, N);
    scanB_kernel<<<1, 128, 0, stream>>>(blksum, NB);
    scanC_kernel<<<(N + 255) / 256, 256, 0, stream>>>(row_ptr, blksum, N, E);
    scatter_kernel<<<(E + 255) / 256, 256, 0, stream>>>(eidx, row_ptr, cnt, csr, flag, E);

    const float* X = x;
    for (int l = 0; l < L; ++l) {
        matmul_kernel<<<N / 32, 256, 0, stream>>>(X, conv_w + (size_t)l * DD * DD, h1, N);
        agg_kernel<<<(N * 32 + 255) / 256, 256, 0, stream>>>(
            h1, row_ptr, csr, dinv,
            conv_b + (size_t)l * DD, gamma + (size_t)l * DD, beta + (size_t)l * DD,
            mean + (size_t)l * DD, var + (size_t)l * DD,
            h_cur, jk, (l == 0) ? 1 : 0, N);
        X = h_cur;
    }
    final_kernel<<<(N + 255) / 256, 256, 0, stream>>>(jk, lin_w, lin_b, out, N);
}

// Round 3
// 556.782 us; speedup vs baseline: 1.8155x; 1.3784x over previous
//
#include <hip/hip_runtime.h>
#include <math.h>

#define DD 128
#define CC 40

typedef __bf16 bf16x8 __attribute__((ext_vector_type(8)));
typedef float f32x4 __attribute__((ext_vector_type(4)));

union BF8 { uint4 q; bf16x8 v; ushort us[8]; };

static __device__ __forceinline__ ushort f2bf(float x) {
    union { float f; unsigned u; } v; v.f = x;
    unsigned r = (v.u + 0x7FFFu + ((v.u >> 16) & 1u)) >> 16;   // RNE
    return (ushort)r;
}
static __device__ __forceinline__ float bf2f(ushort u) {
    union { unsigned u; float f; } v; v.u = ((unsigned)u) << 16;
    return v.f;
}

// ---------------------------------------------------------------------------
// Detect edge_index storage: int32 vs int64 (odd 32-bit words all zero).
__global__ void detect_kernel(const unsigned* __restrict__ e, int* __restrict__ flag) {
    int t = threadIdx.x;
    unsigned nz = 0;
    for (int j = 0; j < 16; ++j) nz |= e[2 * (t * 16 + j) + 1];
    unsigned long long b = __ballot(nz != 0);
    if (t == 0) *flag = (b != 0) ? 1 : 0;
}

__device__ __forceinline__ int edge_at(const void* eptr, int is32, long long idx) {
    if (is32) return ((const int*)eptr)[idx];
    return (int)((const long long*)eptr)[idx];
}

__global__ void hist_kernel(const void* __restrict__ eptr, int* __restrict__ cnt,
                            const int* __restrict__ flag, int E) {
    int e = blockIdx.x * blockDim.x + threadIdx.x;
    if (e >= E) return;
    int is32 = *flag;
    int r = edge_at(eptr, is32, e);
    atomicAdd(&cnt[r], 1);
}

// Hierarchical exclusive scan (1024/block): local scan + block sums.
__global__ __launch_bounds__(1024) void scanA_kernel(int* __restrict__ cnt,
                                                     int* __restrict__ row_ptr,
                                                     float* __restrict__ dinv,
                                                     int* __restrict__ blksum, int N) {
    __shared__ int swave[16];
    int tid = threadIdx.x;
    int lane = tid & 63, wid = tid >> 6;
    int i = blockIdx.x * 1024 + tid;
    int v = (i < N) ? cnt[i] : 0;
    int incl = v;
#pragma unroll
    for (int off = 1; off < 64; off <<= 1) {
        int t = __shfl_up(incl, off);
        if (lane >= off) incl += t;
    }
    if (lane == 63) swave[wid] = incl;
    __syncthreads();
    if (tid < 16) {
        int t = swave[tid];
#pragma unroll
        for (int off = 1; off < 16; off <<= 1) {
            int u = __shfl_up(t, off);
            if (tid >= off) t += u;
        }
        swave[tid] = t;
    }
    __syncthreads();
    int waveoff = (wid == 0) ? 0 : swave[wid - 1];
    if (i < N) {
        row_ptr[i] = waveoff + incl - v;
        dinv[i] = rsqrtf((float)v + 1.0f);
        cnt[i] = 0;
    }
    if (tid == 0) blksum[blockIdx.x] = swave[15];
}

__global__ __launch_bounds__(128) void scanB_kernel(int* __restrict__ blksum, int nb) {
    __shared__ int s[128];
    int t = threadIdx.x;
    int orig = (t < nb) ? blksum[t] : 0;
    s[t] = orig;
    __syncthreads();
    for (int off = 1; off < 128; off <<= 1) {
        int v = (t >= off) ? s[t - off] : 0;
        __syncthreads();
        s[t] += v;
        __syncthreads();
    }
    if (t < nb) blksum[t] = s[t] - orig;
}

__global__ void scanC_kernel(int* __restrict__ row_ptr, const int* __restrict__ blksum,
                             int N, int E) {
    int i = blockIdx.x * blockDim.x + threadIdx.x;
    if (i < N) row_ptr[i] += blksum[i >> 10];
    if (i == 0) row_ptr[N] = E;
}

__global__ void scatter_kernel(const void* __restrict__ eptr, const int* __restrict__ row_ptr,
                               int* __restrict__ cursor, int* __restrict__ csr,
                               const int* __restrict__ flag, int E) {
    int e = blockIdx.x * blockDim.x + threadIdx.x;
    if (e >= E) return;
    int is32 = *flag;
    int r = edge_at(eptr, is32, e);
    int c = edge_at(eptr, is32, (long long)E + e);
    int pos = row_ptr[r] + atomicAdd(&cursor[r], 1);
    csr[pos] = c;
}

// ---------------------------------------------------------------------------
// fp32 -> bf16 conversions
__global__ void cvtx_kernel(const float* __restrict__ x, ushort* __restrict__ xb, long n4) {
    long i = (long)blockIdx.x * blockDim.x + threadIdx.x;
    if (i >= n4) return;
    float4 v = *(const float4*)&x[i * 4];
    ushort4 o;
    o.x = f2bf(v.x); o.y = f2bf(v.y); o.z = f2bf(v.z); o.w = f2bf(v.w);
    *(ushort4*)&xb[i * 4] = o;
}

// Wt[l][col][k] = W[l][k][col] (bf16, K-major for MFMA B frags)
__global__ void cvtw_kernel(const float* __restrict__ W, ushort* __restrict__ Wt, int total) {
    int idx = blockIdx.x * 256 + threadIdx.x;
    if (idx >= total) return;
    int l = idx >> 14, rem = idx & 16383, k = rem >> 7, col = rem & 127;
    Wt[(l << 14) + col * DD + k] = f2bf(W[idx]);
}

// ---------------------------------------------------------------------------
// Y[NPAD,128](bf16) = X[NPAD,128](bf16) @ W -> via Wt[col][k].
// Block 256 = 4 waves; wave owns 16 rows x 128 cols = 8 MFMA 16x16 tiles.
// A frag: row = lane&15, k = 8*(lane>>4)+i (blocked). B frag: col = lane&15, same k.
// D: col = lane&15, row = 4*(lane>>4)+reg  [m89-verified].
__global__ __launch_bounds__(256) void mm_kernel(const ushort* __restrict__ Xb,
                                                 const ushort* __restrict__ Wt,
                                                 ushort* __restrict__ Y, int N) {
    int wave = threadIdx.x >> 6, lane = threadIdx.x & 63;
    int row0 = blockIdx.x * 64 + wave * 16;
    int lrow = lane & 15, kgrp = lane >> 4;
    const ushort* arow = &Xb[(size_t)(row0 + lrow) * DD + kgrp * 8];
    f32x4 acc[8];
#pragma unroll
    for (int j = 0; j < 8; ++j) acc[j] = (f32x4){0.f, 0.f, 0.f, 0.f};
#pragma unroll
    for (int kc = 0; kc < 4; ++kc) {
        BF8 a;
        a.q = *(const uint4*)&arow[kc * 32];
#pragma unroll
        for (int j = 0; j < 8; ++j) {
            BF8 b;
            b.q = *(const uint4*)&Wt[(size_t)(j * 16 + lrow) * DD + kc * 32 + kgrp * 8];
            acc[j] = __builtin_amdgcn_mfma_f32_16x16x32_bf16(a.v, b.v, acc[j], 0, 0, 0);
        }
    }
#pragma unroll
    for (int j = 0; j < 8; ++j) {
        int col = j * 16 + lrow;
#pragma unroll
        for (int r = 0; r < 4; ++r) {
            int row = row0 + kgrp * 4 + r;
            if (row < N) Y[(size_t)row * DD + col] = f2bf(acc[j][r]);
        }
    }
}

// ---------------------------------------------------------------------------
// Fused CSR gather-agg + self loop + bias + BN + ReLU; bf16 in/out, fp32 accum.
// 16 lanes per node; each lane owns 8 channels (16 B).
__global__ __launch_bounds__(256) void agg_kernel(
    const ushort* __restrict__ h1b, const int* __restrict__ row_ptr,
    const int* __restrict__ csr, const float* __restrict__ dinv,
    const float* __restrict__ bias, const float* __restrict__ gamma,
    const float* __restrict__ beta, const float* __restrict__ mean,
    const float* __restrict__ var, ushort* __restrict__ hout, int N) {
    int gid = (blockIdx.x * blockDim.x + threadIdx.x) >> 4;
    if (gid >= N) return;
    int lane = threadIdx.x & 15;
    int c = lane * 8;

    float acc[8];
#pragma unroll
    for (int i = 0; i < 8; ++i) acc[i] = 0.f;

    int s = row_ptr[gid], e = row_ptr[gid + 1];
    for (int p = s; p < e; ++p) {
        int src = csr[p];
        float w = dinv[src];
        BF8 hv;
        hv.q = *(const uint4*)&h1b[(size_t)src * DD + c];
#pragma unroll
        for (int i = 0; i < 8; ++i) acc[i] = fmaf(w, bf2f(hv.us[i]), acc[i]);
    }
    float di = dinv[gid];
    float sn = di * di;
    BF8 sv;
    sv.q = *(const uint4*)&h1b[(size_t)gid * DD + c];

    float bb[8], gg[8], be[8], mm[8], vv[8];
    *(float4*)&bb[0] = *(const float4*)&bias[c];  *(float4*)&bb[4] = *(const float4*)&bias[c + 4];
    *(float4*)&gg[0] = *(const float4*)&gamma[c]; *(float4*)&gg[4] = *(const float4*)&gamma[c + 4];
    *(float4*)&be[0] = *(const float4*)&beta[c];  *(float4*)&be[4] = *(const float4*)&beta[c + 4];
    *(float4*)&mm[0] = *(const float4*)&mean[c];  *(float4*)&mm[4] = *(const float4*)&mean[c + 4];
    *(float4*)&vv[0] = *(const float4*)&var[c];   *(float4*)&vv[4] = *(const float4*)&var[c + 4];

    BF8 o;
#pragma unroll
    for (int i = 0; i < 8; ++i) {
        float h = fmaf(di, acc[i], fmaf(sn, bf2f(sv.us[i]), bb[i]));
        float y = fmaxf(gg[i] * (h - mm[i]) * rsqrtf(vv[i] + 1e-5f) + be[i], 0.f);
        o.us[i] = f2bf(y);
    }
    *(uint4*)&hout[(size_t)gid * DD + c] = o.q;
}

// ---------------------------------------------------------------------------
// out = log_softmax( max_l h_l @ lin_w + lin_b ). 256 nodes/block.
// JK-max fused into the bf16 staging loads.
__global__ __launch_bounds__(256) void final_kernel(const ushort* __restrict__ hall,
                                                    size_t hstride, int L,
                                                    const float* __restrict__ lw,
                                                    const float* __restrict__ lb,
                                                    float* __restrict__ out, int N) {
    __shared__ float Ws[DD][CC];     // 20 KB
    __shared__ float Xs[32][260];    // 32.5 KB
    __shared__ float lbS[CC];
    int t = threadIdx.x;
    for (int i = t; i < DD * CC; i += 256) Ws[i / CC][i % CC] = lw[i];
    if (t < CC) lbS[t] = lb[t];
    int base = blockIdx.x * 256;
    int og = t & 3, ng = t >> 2;
    __syncthreads();

    float acc[4][10];
#pragma unroll
    for (int r = 0; r < 4; ++r)
#pragma unroll
        for (int c = 0; c < 10; ++c) acc[r][c] = lbS[og * 10 + c];

    for (int k0 = 0; k0 < DD; k0 += 32) {
        __syncthreads();
#pragma unroll
        for (int chunk = 0; chunk < 4; ++chunk) {
            int f = chunk * 256 + t;       // ushort8 id within slab
            int nl = f >> 2;               // node local 0..255
            int kk = (f & 3) * 8;
            int node = base + nl;
            float mv[8];
#pragma unroll
            for (int i = 0; i < 8; ++i) mv[i] = 0.f;   // ReLU outputs >= 0
            if (node < N) {
                for (int l = 0; l < L; ++l) {
                    BF8 hv;
                    hv.q = *(const uint4*)&hall[(size_t)l * hstride + (size_t)node * DD + k0 + kk];
#pragma unroll
                    for (int i = 0; i < 8; ++i) mv[i] = fmaxf(mv[i], bf2f(hv.us[i]));
                }
            }
#pragma unroll
            for (int i = 0; i < 8; ++i) Xs[kk + i][nl] = mv[i];
        }
        __syncthreads();
#pragma unroll 4
        for (int kk = 0; kk < 32; ++kk) {
            float4 xv = *(const float4*)&Xs[kk][ng * 4];
#pragma unroll
            for (int cc2 = 0; cc2 < 5; ++cc2) {
                float2 w2 = *(const float2*)&Ws[k0 + kk][og * 10 + cc2 * 2];
                int c0 = cc2 * 2, c1 = cc2 * 2 + 1;
                acc[0][c0] = fmaf(xv.x, w2.x, acc[0][c0]);
                acc[1][c0] = fmaf(xv.y, w2.x, acc[1][c0]);
                acc[2][c0] = fmaf(xv.z, w2.x, acc[2][c0]);
                acc[3][c0] = fmaf(xv.w, w2.x, acc[3][c0]);
                acc[0][c1] = fmaf(xv.x, w2.y, acc[0][c1]);
                acc[1][c1] = fmaf(xv.y, w2.y, acc[1][c1]);
                acc[2][c1] = fmaf(xv.z, w2.y, acc[2][c1]);
                acc[3][c1] = fmaf(xv.w, w2.y, acc[3][c1]);
            }
        }
    }

#pragma unroll
    for (int r = 0; r < 4; ++r) {
        int node = base + ng * 4 + r;
        float m = acc[r][0];
#pragma unroll
        for (int c = 1; c < 10; ++c) m = fmaxf(m, acc[r][c]);
        m = fmaxf(m, __shfl_xor(m, 1));
        m = fmaxf(m, __shfl_xor(m, 2));
        float s = 0.f;
#pragma unroll
        for (int c = 0; c < 10; ++c) s += expf(acc[r][c] - m);
        s += __shfl_xor(s, 1);
        s += __shfl_xor(s, 2);
        float lg = logf(s);
        if (node < N) {
#pragma unroll
            for (int c = 0; c < 10; ++c)
                out[(size_t)node * CC + og * 10 + c] = acc[r][c] - m - lg;
        }
    }
}

// ---------------------------------------------------------------------------
extern "C" void kernel_launch(void* const* d_in, const int* in_sizes, int n_in,
                              void* d_out, int out_size, void* d_ws, size_t ws_size,
                              hipStream_t stream) {
    const float* x      = (const float*)d_in[0];
    const void*  eidx   = d_in[1];
    const float* conv_w = (const float*)d_in[2];
    const float* conv_b = (const float*)d_in[3];
    const float* gamma  = (const float*)d_in[4];
    const float* beta   = (const float*)d_in[5];
    const float* mean   = (const float*)d_in[6];
    const float* var    = (const float*)d_in[7];
    const float* lin_w  = (const float*)d_in[8];
    const float* lin_b  = (const float*)d_in[9];
    float* out = (float*)d_out;

    const int N = in_sizes[0] / DD;          // 100000
    const int E = in_sizes[1] / 2;           // 800000
    const int L = in_sizes[3] / DD;          // 5
    const int NPAD = (N + 63) & ~63;         // 100032
    const size_t hstride = (size_t)NPAD * DD;
    const int NB = (N + 1023) / 1024;

    char* p = (char*)d_ws;
    auto alloc = [&](size_t bytes) -> char* {
        char* r = p;
        p += (bytes + 255) & ~(size_t)255;
        return r;
    };
    ushort* xb     = (ushort*)alloc(hstride * 2);            // matmul out / layer0 in
    ushort* hall   = (ushort*)alloc((size_t)L * hstride * 2);
    ushort* Wt     = (ushort*)alloc((size_t)L * DD * DD * 2);
    float*  dinv   = (float*)alloc((size_t)N * 4);
    int*    row_ptr= (int*)alloc((size_t)(N + 1) * 4);
    int*    cnt    = (int*)alloc((size_t)N * 4);
    int*    csr    = (int*)alloc((size_t)E * 4);
    int*    blksum = (int*)alloc(128 * 4);
    int*    flag   = (int*)alloc(4);

    detect_kernel<<<1, 64, 0, stream>>>((const unsigned*)eidx, flag);
    hipMemsetAsync(cnt, 0, (size_t)N * 4, stream);
    hist_kernel<<<(E + 255) / 256, 256, 0, stream>>>(eidx, cnt, flag, E);
    scanA_kernel<<<NB, 1024, 0, stream>>>(cnt, row_ptr, dinv, blksum, N);
    scanB_kernel<<<1, 128, 0, stream>>>(blksum, NB);
    scanC_kernel<<<(N + 255) / 256, 256, 0, stream>>>(row_ptr, blksum, N, E);
    scatter_kernel<<<(E + 255) / 256, 256, 0, stream>>>(eidx, row_ptr, cnt, csr, flag, E);

    cvtx_kernel<<<(int)(((size_t)N * DD / 4 + 255) / 256), 256, 0, stream>>>(x, xb, (long)N * DD / 4);
    cvtw_kernel<<<(L * DD * DD + 255) / 256, 256, 0, stream>>>(conv_w, Wt, L * DD * DD);

    const ushort* X = xb;
    for (int l = 0; l < L; ++l) {
        // mm writes xb; layer 0 is safely in-place (each block reads only its own rows,
        // all A-reads precede its stores).
        mm_kernel<<<NPAD / 64, 256, 0, stream>>>(X, Wt + (size_t)l * DD * DD, xb, N);
        ushort* hl = hall + (size_t)l * hstride;
        agg_kernel<<<(N * 16 + 255) / 256, 256, 0, stream>>>(
            xb, row_ptr, csr, dinv,
            conv_b + (size_t)l * DD, gamma + (size_t)l * DD, beta + (size_t)l * DD,
            mean + (size_t)l * DD, var + (size_t)l * DD, hl, N);
        X = hl;
    }
    final_kernel<<<(N + 255) / 256, 256, 0, stream>>>(hall, hstride, L, lin_w, lin_b, out, N);
}